// Round 2
// baseline (708.710 us; speedup 1.0000x reference)
//
#include <hip/hip_runtime.h>
#include <math.h>

// ContextAwareFlowRouter: B=4,S=1024,IN=OUT=128,P=16, D=16384, MAX_SEQ=4096
// Strategy: full fp64 pipeline so the top-k ranking matches the harness's
// float64 numpy reference to ~1e-16 (rank gaps are ~1e-6 — no flips).
#define S_      1024
#define D_      16384

typedef float  v4f __attribute__((ext_vector_type(4)));
typedef double v4d __attribute__((ext_vector_type(4)));

__device__ __forceinline__ double gelu64(double v) {
    return 0.5 * v * (1.0 + erf(v * 0.70710678118654752440));
}
__device__ __forceinline__ double sigmoid64(double z) {
    return 1.0 / (1.0 + exp(-z));
}

// ---------------- kernel 1: per-token selector softmax + intensity ----------
// grid 256 blocks x 256 thr; block handles 16 tokens. All math fp64.
__global__ __launch_bounds__(256) void mlp_kernel(
    const float* __restrict__ x, const float* __restrict__ ctx,
    const float* __restrict__ w_sel1, const float* __restrict__ b_sel1,
    const float* __restrict__ w_sel2, const float* __restrict__ b_sel2,
    const float* __restrict__ w_int1, const float* __restrict__ b_int1,
    const float* __restrict__ w_int2, const float* __restrict__ b_int2,
    double* __restrict__ pw_out, double* __restrict__ int_out)
{
    __shared__ double comb[16][256];
    __shared__ double h1[16][32];
    const int tid = threadIdx.x;
    const int tok0 = blockIdx.x * 16;

    for (int idx = tid; idx < 16 * 256; idx += 256) {
        int tok = idx >> 8, i = idx & 255;
        comb[tok][i] = (double)((i < 128) ? x[(tok0 + tok) * 128 + i]
                                          : ctx[(tok0 + tok) * 128 + (i - 128)]);
    }
    __syncthreads();

    // h1 = gelu(comb @ w_sel1 + b_sel1)  [16][32]
    for (int rep = 0; rep < 2; ++rep) {
        int idx = tid + rep * 256;
        int tok = idx >> 5, u = idx & 31;
        double s = (double)b_sel1[u];
        for (int i = 0; i < 256; ++i)
            s = fma(comb[tok][i], (double)w_sel1[i * 32 + u], s);
        h1[tok][u] = gelu64(s);
    }
    __syncthreads();

    // logits -> softmax over P=16 (16-lane groups inside a wave)
    {
        int tok = tid >> 4, u = tid & 15;
        double z = (double)b_sel2[u];
        for (int j = 0; j < 32; ++j)
            z = fma(h1[tok][j], (double)w_sel2[j * 16 + u], z);
        double m = z;
        for (int off = 8; off >= 1; off >>= 1)
            m = fmax(m, __shfl_xor(m, off));
        double e = exp(z - m);
        double ssum = e;
        for (int off = 8; off >= 1; off >>= 1)
            ssum += __shfl_xor(ssum, off);
        pw_out[(tok0 + tok) * 16 + u] = e / ssum;
    }

    // intensity = sigmoid(gelu(comb @ w_int1 + b_int1) @ w_int2 + b_int2)
    for (int pass = 0; pass < 4; ++pass) {
        int wv = tid >> 6, lane = tid & 63;
        int tok = pass * 4 + wv;
        double s = (double)b_int1[lane];
        for (int i = 0; i < 256; ++i)
            s = fma(comb[tok][i], (double)w_int1[i * 64 + lane], s);
        double c = gelu64(s) * (double)w_int2[lane];
        for (int off = 32; off >= 1; off >>= 1)
            c += __shfl_xor(c, off);
        if (lane == 0)
            int_out[tok0 + tok] = sigmoid64(c + (double)b_int2[0]);
    }
}

// ---------------- kernel 2: adaptive window per batch (fp64) ---------------
__global__ __launch_bounds__(256) void win_kernel(
    const float* __restrict__ x,
    const float* __restrict__ w_win1, const float* __restrict__ b_win1,
    const float* __restrict__ w_win2, const float* __restrict__ b_win2,
    double* __restrict__ win_out)
{
    __shared__ double acc2[2][128];
    __shared__ double xm[128];
    const int tid = threadIdx.x;
    const int b = blockIdx.x;
    int i = tid & 127, h = tid >> 7;
    double a = 0.0;
    for (int s = h; s < S_; s += 2)
        a += (double)x[(b * S_ + s) * 128 + i];
    acc2[h][i] = a;
    __syncthreads();
    if (tid < 128)
        xm[tid] = (acc2[0][tid] + acc2[1][tid]) * (1.0 / 1024.0);
    __syncthreads();
    if (tid < 64) {
        double s = (double)b_win1[tid];
        for (int i2 = 0; i2 < 128; ++i2)
            s = fma(xm[i2], (double)w_win1[i2 * 64 + tid], s);
        double c = gelu64(s) * (double)w_win2[tid];
        for (int off = 32; off >= 1; off >>= 1)
            c += __shfl_xor(c, off);
        if (tid == 0)
            win_out[b] = sigmoid64(c + (double)b_win2[0]) * 3840.0 + 256.0;
    }
}

// ---------------- kernel 3: fp64 flow + exact fp64 top-k + masked write ----
// grid 4096 blocks x 256 thr; block handles 1 token; 64 fp64 values/thread.
__global__ __launch_bounds__(256, 2) void flow_kernel(
    const float* __restrict__ patterns,
    const double* __restrict__ pw_buf, const double* __restrict__ int_buf,
    const double* __restrict__ win_buf,
    float* __restrict__ out)
{
    __shared__ int sred[2][4];
    const int tid = threadIdx.x;
    const int tok = blockIdx.x;
    const int lane = tid & 63, wv = tid >> 6;

    // k = max(1, floor(16384 * 0.1 * mean(window/4096)))  (fp64, np order)
    double w0 = win_buf[0] * (1.0 / 4096.0);
    double w1 = win_buf[1] * (1.0 / 4096.0);
    double w2 = win_buf[2] * (1.0 / 4096.0);
    double w3 = win_buf[3] * (1.0 / 4096.0);
    double mean = (((w0 + w1) + w2) + w3) * 0.25;
    double kd = floor(16384.0 * (0.1 * mean));
    int k = (kd < 1.0) ? 1 : (int)kd;

    double pwl[16];
#pragma unroll
    for (int p = 0; p < 16; ++p)
        pwl[p] = pw_buf[tok * 16 + p];
    double it = int_buf[tok];

    const v4f* pat4 = (const v4f*)patterns;
    v4d v[16];
#pragma unroll
    for (int c = 0; c < 16; ++c) {
        int grp = c * 256 + tid;
        v4d a;
        a.x = 0.0; a.y = 0.0; a.z = 0.0; a.w = 0.0;
#pragma unroll
        for (int p = 0; p < 16; ++p) {
            v4f pp = pat4[p * 4096 + grp];
            a.x = fma(pwl[p], (double)pp.x, a.x);
            a.y = fma(pwl[p], (double)pp.y, a.y);
            a.z = fma(pwl[p], (double)pp.z, a.z);
            a.w = fma(pwl[p], (double)pp.w, a.w);
        }
        v[c].x = a.x * it; v[c].y = a.y * it;
        v[c].z = a.z * it; v[c].w = a.w * it;
    }

    // exact k-th largest |v| in fp64.
    // Stage 1: bisect fp32 candidate space (31 steps, fp64 compares).
    // Monotone: for non-negative floats, float order == uint-key order.
    int par = 0;
    unsigned p32 = 0;
    int cnt = D_;  // count(|v| >= 0) == D
    for (int bit = 30; bit >= 0; --bit) {
        unsigned cand32 = p32 | (1u << bit);
        double cand = (double)__uint_as_float(cand32);
        int n = 0;
#pragma unroll
        for (int c = 0; c < 16; ++c) {
            n += (fabs(v[c].x) >= cand); n += (fabs(v[c].y) >= cand);
            n += (fabs(v[c].z) >= cand); n += (fabs(v[c].w) >= cand);
        }
#pragma unroll
        for (int off = 32; off >= 1; off >>= 1)
            n += __shfl_xor(n, off);
        if (lane == 0) sred[par][wv] = n;
        __syncthreads();
        int tot = sred[par][0] + sred[par][1] + sred[par][2] + sred[par][3];
        par ^= 1;
        if (tot >= k) { p32 = cand32; cnt = tot; }
    }
    double thr = (double)__uint_as_float(p32);

    // Stage 2 (rare; block-uniform): fp32 ties straddle the boundary —
    // refine the remaining 29 double-mantissa bits inside [c, nextafterf(c)).
    if (cnt != k) {
        unsigned long long K = __double_as_longlong(thr);
        for (int bit = 28; bit >= 0; --bit) {
            unsigned long long c64 = K | (1ull << bit);
            double cand = __longlong_as_double(c64);
            int n = 0;
#pragma unroll
            for (int c = 0; c < 16; ++c) {
                n += (fabs(v[c].x) >= cand); n += (fabs(v[c].y) >= cand);
                n += (fabs(v[c].z) >= cand); n += (fabs(v[c].w) >= cand);
            }
#pragma unroll
            for (int off = 32; off >= 1; off >>= 1)
                n += __shfl_xor(n, off);
            if (lane == 0) sred[par][wv] = n;
            __syncthreads();
            int tot = sred[par][0] + sred[par][1] + sred[par][2] + sred[par][3];
            par ^= 1;
            if (tot >= k) K = c64;
        }
        thr = __longlong_as_double(K);
    }

    // masked write, fp64 compare, single fp64->fp32 rounding
    v4f* op = (v4f*)(out + (size_t)tok * D_);
#pragma unroll
    for (int c = 0; c < 16; ++c) {
        int grp = c * 256 + tid;
        v4f r;
        r.x = (fabs(v[c].x) >= thr) ? (float)v[c].x : 0.0f;
        r.y = (fabs(v[c].y) >= thr) ? (float)v[c].y : 0.0f;
        r.z = (fabs(v[c].z) >= thr) ? (float)v[c].z : 0.0f;
        r.w = (fabs(v[c].w) >= thr) ? (float)v[c].w : 0.0f;
        __builtin_nontemporal_store(r, &op[grp]);
    }
}

extern "C" void kernel_launch(void* const* d_in, const int* in_sizes, int n_in,
                              void* d_out, int out_size, void* d_ws, size_t ws_size,
                              hipStream_t stream) {
    const float* x        = (const float*)d_in[0];
    const float* ctx      = (const float*)d_in[1];
    const float* patterns = (const float*)d_in[2];
    const float* w_sel1   = (const float*)d_in[3];
    const float* b_sel1   = (const float*)d_in[4];
    const float* w_sel2   = (const float*)d_in[5];
    const float* b_sel2   = (const float*)d_in[6];
    const float* w_int1   = (const float*)d_in[7];
    const float* b_int1   = (const float*)d_in[8];
    const float* w_int2   = (const float*)d_in[9];
    const float* b_int2   = (const float*)d_in[10];
    const float* w_win1   = (const float*)d_in[11];
    const float* b_win1   = (const float*)d_in[12];
    const float* w_win2   = (const float*)d_in[13];
    const float* b_win2   = (const float*)d_in[14];

    double* ws    = (double*)d_ws;
    double* win   = ws;                  // 4 doubles
    double* pw    = ws + 8;              // 4096*16 doubles
    double* inten = ws + 8 + 65536;      // 4096 doubles
    float*  out   = (float*)d_out;

    hipLaunchKernelGGL(mlp_kernel, dim3(256), dim3(256), 0, stream,
                       x, ctx, w_sel1, b_sel1, w_sel2, b_sel2,
                       w_int1, b_int1, w_int2, b_int2, pw, inten);
    hipLaunchKernelGGL(win_kernel, dim3(4), dim3(256), 0, stream,
                       x, w_win1, b_win1, w_win2, b_win2, win);
    hipLaunchKernelGGL(flow_kernel, dim3(4096), dim3(256), 0, stream,
                       patterns, pw, inten, win, out);
}

// Round 3
// 516.193 us; speedup vs baseline: 1.3730x; 1.3730x over previous
//
#include <hip/hip_runtime.h>
#include <math.h>

// ContextAwareFlowRouter: B=4,S=1024,IN=OUT=128,P=16, D=16384, MAX_SEQ=4096
// fp32 bulk flow values + fp64-exact top-k boundary resolution on a small
// candidate list (mask provably identical to the fp64 numpy reference).
#define S_   1024
#define D_   16384
#define CAPA 192   // bisect early-exit when in-interval count <= CAPA
#define CAPL 256   // candidate list capacity per token

typedef float v4f __attribute__((ext_vector_type(4)));

__device__ __forceinline__ double gelu64(double v) {
    return 0.5 * v * (1.0 + erf(v * 0.70710678118654752440));
}
__device__ __forceinline__ double sigmoid64(double z) {
    return 1.0 / (1.0 + exp(-z));
}

// ---------------- kernel 1: selector softmax + intensity (fp64 math) -------
// 1024 blocks x 256 thr; 4 tokens/block.
__global__ __launch_bounds__(256) void mlp_kernel(
    const float* __restrict__ x, const float* __restrict__ ctx,
    const float* __restrict__ w_sel1, const float* __restrict__ b_sel1,
    const float* __restrict__ w_sel2, const float* __restrict__ b_sel2,
    const float* __restrict__ w_int1, const float* __restrict__ b_int1,
    const float* __restrict__ w_int2, const float* __restrict__ b_int2,
    double* __restrict__ pw64, float* __restrict__ pw32,
    double* __restrict__ it64, float* __restrict__ it32)
{
    __shared__ double comb[4][256];
    __shared__ double hpart[2][4][32];
    __shared__ double h1[4][32];
    const int tid = threadIdx.x;
    const int tok0 = blockIdx.x * 4;

    for (int r = 0; r < 4; ++r) {
        int idx = tid + r * 256;
        int t = idx >> 8, i = idx & 255;
        comb[t][i] = (double)((i < 128) ? x[(tok0 + t) * 128 + i]
                                        : ctx[(tok0 + t) * 128 + (i - 128)]);
    }
    __syncthreads();

    {   // h1 partials: 2 half-dims x 4 tok x 32 units = 256 items
        int u = tid & 31, t = (tid >> 5) & 3, half = tid >> 7;
        int i0 = half * 128;
        double s0 = (half == 0) ? (double)b_sel1[u] : 0.0, s1 = 0.0;
        for (int i = 0; i < 128; i += 2) {
            s0 = fma(comb[t][i0 + i],     (double)w_sel1[(i0 + i) * 32 + u],     s0);
            s1 = fma(comb[t][i0 + i + 1], (double)w_sel1[(i0 + i + 1) * 32 + u], s1);
        }
        hpart[half][t][u] = s0 + s1;
    }
    __syncthreads();
    if (tid < 128) {
        int t = tid >> 5, u = tid & 31;
        h1[t][u] = gelu64(hpart[0][t][u] + hpart[1][t][u]);
    }
    __syncthreads();
    if (tid < 64) {   // softmax over P=16, 16-lane groups in wave 0
        int t = tid >> 4, u = tid & 15;
        double z = (double)b_sel2[u];
        for (int j = 0; j < 32; ++j)
            z = fma(h1[t][j], (double)w_sel2[j * 16 + u], z);
        double m = z;
        for (int off = 8; off >= 1; off >>= 1) m = fmax(m, __shfl_xor(m, off));
        double e = exp(z - m);
        double ssum = e;
        for (int off = 8; off >= 1; off >>= 1) ssum += __shfl_xor(ssum, off);
        double pwv = e / ssum;
        pw64[(tok0 + t) * 16 + u] = pwv;
        pw32[(tok0 + t) * 16 + u] = (float)pwv;
    }
    {   // intensity: wave per token, 64 units/lane
        int t = tid >> 6, u = tid & 63;
        double a0 = (double)b_int1[u], a1 = 0.0, a2 = 0.0, a3 = 0.0;
        for (int i = 0; i < 256; i += 4) {
            a0 = fma(comb[t][i],     (double)w_int1[i * 64 + u],       a0);
            a1 = fma(comb[t][i + 1], (double)w_int1[(i + 1) * 64 + u], a1);
            a2 = fma(comb[t][i + 2], (double)w_int1[(i + 2) * 64 + u], a2);
            a3 = fma(comb[t][i + 3], (double)w_int1[(i + 3) * 64 + u], a3);
        }
        double c = gelu64((a0 + a1) + (a2 + a3)) * (double)w_int2[u];
        for (int off = 32; off >= 1; off >>= 1) c += __shfl_xor(c, off);
        if (u == 0) {
            double iv = sigmoid64(c + (double)b_int2[0]);
            it64[tok0 + t] = iv;
            it32[tok0 + t] = (float)iv;
        }
    }
}

// ---------------- kernel 2a: x.mean(axis=1) partial sums -------------------
// 64 blocks (4 b x 16 chunks) x 256 thr
__global__ __launch_bounds__(256) void win_part_kernel(
    const float* __restrict__ x, double* __restrict__ wpart)
{
    __shared__ double red[2][128];
    const int tid = threadIdx.x;
    const int b = blockIdx.x >> 4, chunk = blockIdx.x & 15;
    int i = tid & 127, h = tid >> 7;
    double a0 = 0.0, a1 = 0.0;
    int s0 = b * S_ + chunk * 64 + h * 32;
    for (int j = 0; j < 32; j += 2) {
        a0 += (double)x[(s0 + j) * 128 + i];
        a1 += (double)x[(s0 + j + 1) * 128 + i];
    }
    red[h][i] = a0 + a1;
    __syncthreads();
    if (tid < 128)
        wpart[(b * 16 + chunk) * 128 + tid] = red[0][tid] + red[1][tid];
}

// ---------------- kernel 2b: finish window MLP -----------------------------
// 1 block x 256 thr (wave per b)
__global__ __launch_bounds__(256) void win_fin_kernel(
    const double* __restrict__ wpart,
    const float* __restrict__ w_win1, const float* __restrict__ b_win1,
    const float* __restrict__ w_win2, const float* __restrict__ b_win2,
    double* __restrict__ win_out)
{
    __shared__ double xm[4][128];
    const int tid = threadIdx.x;
    const int b = tid >> 6, lane = tid & 63;
    for (int r = 0; r < 2; ++r) {
        int i = lane + r * 64;
        double s = 0.0;
        for (int c = 0; c < 16; ++c)
            s += wpart[(b * 16 + c) * 128 + i];
        xm[b][i] = s * (1.0 / 1024.0);
    }
    __syncthreads();
    {
        int u = lane;
        double s0 = (double)b_win1[u], s1 = 0.0;
        for (int i = 0; i < 128; i += 2) {
            s0 = fma(xm[b][i],     (double)w_win1[i * 64 + u],       s0);
            s1 = fma(xm[b][i + 1], (double)w_win1[(i + 1) * 64 + u], s1);
        }
        double c = gelu64(s0 + s1) * (double)w_win2[u];
        for (int off = 32; off >= 1; off >>= 1) c += __shfl_xor(c, off);
        if (lane == 0)
            win_out[b] = sigmoid64(c + (double)b_win2[0]) * 3840.0 + 256.0;
    }
}

// ---------------- kernel 3: fp32 flow + exact top-k mask + write -----------
// 2048 blocks x 256 thr; 2 tokens/block, 64 fp32 values/thread/token.
__global__ __launch_bounds__(256, 3) void flow_kernel(
    const float* __restrict__ patterns,
    const double* __restrict__ pw64, const float* __restrict__ pw32,
    const double* __restrict__ it64, const float* __restrict__ it32,
    const double* __restrict__ win,
    float* __restrict__ out)
{
    __shared__ int sred[2][4];
    __shared__ float smax[2][4];
    __shared__ unsigned listIdx[2][CAPL];
    __shared__ double listVal[2][CAPL];
    __shared__ unsigned flagBits[2][512];
    __shared__ unsigned listCnt[2];

    const int tid = threadIdx.x;
    const int lane = tid & 63, wv = tid >> 6;
    const int t0 = blockIdx.x * 2, t1 = t0 + 1;

    if (tid < 2) listCnt[tid] = 0;
    for (int r = tid; r < 1024; r += 256) flagBits[r >> 9][r & 511] = 0;

    // k = max(1, floor(16384 * 0.1 * mean(window/4096)))  (np fp64 order)
    double w0 = win[0] * (1.0 / 4096.0), w1 = win[1] * (1.0 / 4096.0);
    double w2 = win[2] * (1.0 / 4096.0), w3 = win[3] * (1.0 / 4096.0);
    double mean = (((w0 + w1) + w2) + w3) * 0.25;
    double kd = floor(16384.0 * (0.1 * mean));
    int k = (kd < 1.0) ? 1 : (int)kd;

    float qw0[16], qw1[16];
#pragma unroll
    for (int p = 0; p < 16; ++p) {
        qw0[p] = pw32[t0 * 16 + p];
        qw1[p] = pw32[t1 * 16 + p];
    }
    float i0 = it32[t0], i1 = it32[t1];

    const v4f* pat4 = (const v4f*)patterns;
    v4f v0[16], v1[16];
#pragma unroll
    for (int c = 0; c < 16; ++c) {
        int grp = c * 256 + tid;
        v4f a0 = (v4f)(0.0f), a1 = (v4f)(0.0f);
#pragma unroll
        for (int p = 0; p < 16; ++p) {
            v4f pp = pat4[p * 4096 + grp];
            a0 += qw0[p] * pp;
            a1 += qw1[p] * pp;
        }
        v0[c] = a0 * i0;
        v1[c] = a1 * i1;
    }

    // per-token max |v| (shrinks bisection range)
    float mx0 = 0.0f, mx1 = 0.0f;
#pragma unroll
    for (int c = 0; c < 16; ++c) {
        mx0 = fmaxf(mx0, fmaxf(fmaxf(fabsf(v0[c].x), fabsf(v0[c].y)),
                               fmaxf(fabsf(v0[c].z), fabsf(v0[c].w))));
        mx1 = fmaxf(mx1, fmaxf(fmaxf(fabsf(v1[c].x), fabsf(v1[c].y)),
                               fmaxf(fabsf(v1[c].z), fabsf(v1[c].w))));
    }
    for (int off = 32; off >= 1; off >>= 1) {
        mx0 = fmaxf(mx0, __shfl_xor(mx0, off));
        mx1 = fmaxf(mx1, __shfl_xor(mx1, off));
    }
    if (lane == 0) { smax[0][wv] = mx0; smax[1][wv] = mx1; }
    __syncthreads();
    mx0 = fmaxf(fmaxf(smax[0][0], smax[0][1]), fmaxf(smax[0][2], smax[0][3]));
    mx1 = fmaxf(fmaxf(smax[1][0], smax[1][1]), fmaxf(smax[1][2], smax[1][3]));

    // midpoint bisection on fp32 |v| uint keys (monotone for v>=0),
    // early exit when candidate interval holds <= CAPA elements.
    unsigned lo0 = 0, hi0 = __float_as_uint(mx0) + 1;
    unsigned lo1 = 0, hi1 = __float_as_uint(mx1) + 1;
    int clo0 = D_, chi0 = 0, clo1 = D_, chi1 = 0;
    int par = 0;
    while (((clo0 - chi0 > CAPA) && (hi0 - lo0 > 1)) ||
           ((clo1 - chi1 > CAPA) && (hi1 - lo1 > 1))) {
        unsigned c0k = (lo0 + hi0) >> 1, c1k = (lo1 + hi1) >> 1;
        float c0 = __uint_as_float(c0k), c1 = __uint_as_float(c1k);
        int n0 = 0, n1 = 0;
#pragma unroll
        for (int c = 0; c < 16; ++c) {
            n0 += (fabsf(v0[c].x) >= c0); n0 += (fabsf(v0[c].y) >= c0);
            n0 += (fabsf(v0[c].z) >= c0); n0 += (fabsf(v0[c].w) >= c0);
            n1 += (fabsf(v1[c].x) >= c1); n1 += (fabsf(v1[c].y) >= c1);
            n1 += (fabsf(v1[c].z) >= c1); n1 += (fabsf(v1[c].w) >= c1);
        }
        int pk = n0 | (n1 << 16);
#pragma unroll
        for (int off = 32; off >= 1; off >>= 1) pk += __shfl_xor(pk, off);
        if (lane == 0) sred[par][wv] = pk;
        __syncthreads();
        int tot = sred[par][0] + sred[par][1] + sred[par][2] + sred[par][3];
        par ^= 1;
        int tc0 = tot & 0xffff, tc1 = tot >> 16;
        if (hi0 - lo0 > 1) { if (tc0 >= k) { lo0 = c0k; clo0 = tc0; } else { hi0 = c0k; chi0 = tc0; } }
        if (hi1 - lo1 > 1) { if (tc1 >= k) { lo1 = c1k; clo1 = tc1; } else { hi1 = c1k; chi1 = tc1; } }
    }

    // margins: E bounds |v32 - a64| (fp32 dot + cast noise), scale-invariant
    float E0 = 3e-6f * i0, E1 = 3e-6f * i1;
    float loCut0 = __uint_as_float(lo0) - 2.0f * E0, hiCut0 = __uint_as_float(hi0) + 2.0f * E0;
    float loCut1 = __uint_as_float(lo1) - 2.0f * E1, hiCut1 = __uint_as_float(hi1) + 2.0f * E1;

    // sure-in count + candidate collection
    int ns0 = 0, ns1 = 0;
#pragma unroll
    for (int c = 0; c < 16; ++c) {
#pragma unroll
        for (int q = 0; q < 4; ++q) {
            unsigned e = (unsigned)(4 * (c * 256 + tid) + q);
            float a0 = fabsf(v0[c][q]);
            if (a0 >= hiCut0) ns0++;
            else if (a0 >= loCut0) {
                unsigned pos = atomicAdd(&listCnt[0], 1u);
                if (pos < CAPL) listIdx[0][pos] = e;
            }
            float a1 = fabsf(v1[c][q]);
            if (a1 >= hiCut1) ns1++;
            else if (a1 >= loCut1) {
                unsigned pos = atomicAdd(&listCnt[1], 1u);
                if (pos < CAPL) listIdx[1][pos] = e;
            }
        }
    }
    {
        int pk = ns0 | (ns1 << 16);
#pragma unroll
        for (int off = 32; off >= 1; off >>= 1) pk += __shfl_xor(pk, off);
        if (lane == 0) sred[par][wv] = pk;
    }
    __syncthreads();
    int tot = sred[par][0] + sred[par][1] + sred[par][2] + sred[par][3];
    int m0 = k - (tot & 0xffff), m1 = k - (tot >> 16);
    int c0n = (int)(listCnt[0] < CAPL ? listCnt[0] : CAPL);
    int c1n = (int)(listCnt[1] < CAPL ? listCnt[1] : CAPL);

    // fp64-exact values for candidates (matches np ranking to ~1e-15)
    double itt0 = it64[t0], itt1 = it64[t1];
    int totL = c0n + c1n;
    for (int g = tid; g < totL; g += 256) {
        int tk = (g >= c0n);
        int e = tk ? (g - c0n) : g;
        unsigned idx = listIdx[tk][e];
        const double* pwp = pw64 + (tk ? t1 : t0) * 16;
        double s = 0.0;
#pragma unroll
        for (int p = 0; p < 16; ++p)
            s = fma(pwp[p], (double)patterns[p * D_ + idx], s);
        listVal[tk][e] = fabs(s * (tk ? itt1 : itt0));
    }
    __syncthreads();
    // rank within list; flag = (strict-greater count < m)  [tie-correct]
    for (int g = tid; g < totL; g += 256) {
        int tk = (g >= c0n);
        int e = tk ? (g - c0n) : g;
        double my = listVal[tk][e];
        int cnt = tk ? c1n : c0n, m = tk ? m1 : m0;
        int r = 0;
        for (int j = 0; j < cnt; ++j) r += (listVal[tk][j] > my);
        if (r < m) {
            unsigned idx = listIdx[tk][e];
            atomicOr(&flagBits[tk][idx >> 5], 1u << (idx & 31));
        }
    }
    __syncthreads();

    // masked write
    v4f* o0p = (v4f*)(out + (size_t)t0 * D_);
    v4f* o1p = (v4f*)(out + (size_t)t1 * D_);
#pragma unroll
    for (int c = 0; c < 16; ++c) {
        int grp = c * 256 + tid;
        v4f r0, r1;
#pragma unroll
        for (int q = 0; q < 4; ++q) {
            unsigned e = (unsigned)(4 * grp + q);
            float av = fabsf(v0[c][q]);
            bool keep = (av >= hiCut0);
            if (!keep && av >= loCut0) keep = (flagBits[0][e >> 5] >> (e & 31)) & 1u;
            r0[q] = keep ? v0[c][q] : 0.0f;
            av = fabsf(v1[c][q]);
            keep = (av >= hiCut1);
            if (!keep && av >= loCut1) keep = (flagBits[1][e >> 5] >> (e & 31)) & 1u;
            r1[q] = keep ? v1[c][q] : 0.0f;
        }
        __builtin_nontemporal_store(r0, &o0p[grp]);
        __builtin_nontemporal_store(r1, &o1p[grp]);
    }
}

extern "C" void kernel_launch(void* const* d_in, const int* in_sizes, int n_in,
                              void* d_out, int out_size, void* d_ws, size_t ws_size,
                              hipStream_t stream) {
    const float* x        = (const float*)d_in[0];
    const float* ctx      = (const float*)d_in[1];
    const float* patterns = (const float*)d_in[2];
    const float* w_sel1   = (const float*)d_in[3];
    const float* b_sel1   = (const float*)d_in[4];
    const float* w_sel2   = (const float*)d_in[5];
    const float* b_sel2   = (const float*)d_in[6];
    const float* w_int1   = (const float*)d_in[7];
    const float* b_int1   = (const float*)d_in[8];
    const float* w_int2   = (const float*)d_in[9];
    const float* b_int2   = (const float*)d_in[10];
    const float* w_win1   = (const float*)d_in[11];
    const float* b_win1   = (const float*)d_in[12];
    const float* w_win2   = (const float*)d_in[13];
    const float* b_win2   = (const float*)d_in[14];

    double* ws    = (double*)d_ws;
    double* win   = ws;                   // 8 doubles reserved
    double* pw64  = ws + 8;               // 65536
    double* it64  = pw64 + 65536;         // 4096
    double* wpart = it64 + 4096;          // 8192
    float*  pw32  = (float*)(wpart + 8192);  // 65536 floats
    float*  it32  = pw32 + 65536;            // 4096 floats
    float*  out   = (float*)d_out;

    hipLaunchKernelGGL(mlp_kernel, dim3(1024), dim3(256), 0, stream,
                       x, ctx, w_sel1, b_sel1, w_sel2, b_sel2,
                       w_int1, b_int1, w_int2, b_int2, pw64, pw32, it64, it32);
    hipLaunchKernelGGL(win_part_kernel, dim3(64), dim3(256), 0, stream, x, wpart);
    hipLaunchKernelGGL(win_fin_kernel, dim3(1), dim3(256), 0, stream,
                       wpart, w_win1, b_win1, w_win2, b_win2, win);
    hipLaunchKernelGGL(flow_kernel, dim3(2048), dim3(256), 0, stream,
                       patterns, pw64, pw32, it64, it32, win, out);
}

// Round 4
// 445.215 us; speedup vs baseline: 1.5918x; 1.1594x over previous
//
#include <hip/hip_runtime.h>
#include <math.h>

// ContextAwareFlowRouter: B=4,S=1024,IN=OUT=128,P=16, D=16384, MAX_SEQ=4096
// fp32 bulk flow values + fp64-exact top-k boundary resolution on a small
// candidate list (mask provably identical to the fp64 numpy reference).
#define S_   1024
#define D_   16384
#define CAPL 512   // candidate list capacity per token
#define NB   512   // histogram buckets per token (64/octave, 8 octaves)

typedef float v4f __attribute__((ext_vector_type(4)));

__device__ __forceinline__ double gelu64(double v) {
    return 0.5 * v * (1.0 + erf(v * 0.70710678118654752440));
}
__device__ __forceinline__ double sigmoid64(double z) {
    return 1.0 / (1.0 + exp(-z));
}
__device__ __forceinline__ float rfl(float x) {   // force uniform -> SGPR
    return __uint_as_float(__builtin_amdgcn_readfirstlane(__float_as_uint(x)));
}

// ---------------- kernel 1: selector softmax + intensity (fp64 math) -------
// 2048 blocks x 256 thr; 2 tokens/block; dots split across lanes.
__global__ __launch_bounds__(256) void mlp_kernel(
    const float* __restrict__ x, const float* __restrict__ ctx,
    const float* __restrict__ w_sel1, const float* __restrict__ b_sel1,
    const float* __restrict__ w_sel2, const float* __restrict__ b_sel2,
    const float* __restrict__ w_int1, const float* __restrict__ b_int1,
    const float* __restrict__ w_int2, const float* __restrict__ b_int2,
    double* __restrict__ pw64, float* __restrict__ pw32,
    double* __restrict__ it64, float* __restrict__ it32)
{
    __shared__ double comb[2][256];
    __shared__ double h1[2][32];
    __shared__ double ipart[2][2];
    const int tid = threadIdx.x;
    const int tok0 = blockIdx.x * 2;
    const int t = tid >> 7, local = tid & 127;

    for (int r = 0; r < 2; ++r) {
        int idx = tid + r * 256;
        int tk = idx >> 8, i = idx & 255;
        comb[tk][i] = (double)((i < 128) ? x[(tok0 + tk) * 128 + i]
                                         : ctx[(tok0 + tk) * 128 + (i - 128)]);
    }
    __syncthreads();

    {   // sel1: 32 units x 4 slices of 64
        int u = local >> 2, sl = local & 3;
        int i0 = sl * 64;
        double s0 = (sl == 0) ? (double)b_sel1[u] : 0.0, s1 = 0.0;
        for (int i = 0; i < 64; i += 2) {
            s0 = fma(comb[t][i0 + i],     (double)w_sel1[(i0 + i) * 32 + u],     s0);
            s1 = fma(comb[t][i0 + i + 1], (double)w_sel1[(i0 + i + 1) * 32 + u], s1);
        }
        double s = s0 + s1;
        s += __shfl_xor(s, 1);
        s += __shfl_xor(s, 2);
        if (sl == 0) h1[t][u] = gelu64(s);
    }
    {   // int1: 64 units x 2 slices of 128; then reduce 64 units
        int u = local >> 1, sl = local & 1;
        int i0 = sl * 128;
        double a0 = (sl == 0) ? (double)b_int1[u] : 0.0, a1 = 0.0, a2 = 0.0, a3 = 0.0;
        for (int i = 0; i < 128; i += 4) {
            a0 = fma(comb[t][i0 + i],     (double)w_int1[(i0 + i) * 64 + u],     a0);
            a1 = fma(comb[t][i0 + i + 1], (double)w_int1[(i0 + i + 1) * 64 + u], a1);
            a2 = fma(comb[t][i0 + i + 2], (double)w_int1[(i0 + i + 2) * 64 + u], a2);
            a3 = fma(comb[t][i0 + i + 3], (double)w_int1[(i0 + i + 3) * 64 + u], a3);
        }
        double s = (a0 + a1) + (a2 + a3);
        s += __shfl_xor(s, 1);
        double val = (sl == 0) ? gelu64(s) * (double)w_int2[u] : 0.0;
        for (int off = 2; off <= 32; off <<= 1)
            val += __shfl_xor(val, off);
        val += __shfl_xor(val, 1);   // fold the sl lanes' duplicates? no: sl==1 holds 0
        // NOTE: after xor-1 both lanes of a pair hold same sum; the 6-step butterfly
        // above (2..32 then 1) sums each value exactly once since sl==1 lanes are 0.
        if ((local & 63) == 0) ipart[t][local >> 6] = val;
    }
    __syncthreads();

    if (tid < 32) {   // sel2 + softmax over P=16
        int t2 = tid >> 4, u = tid & 15;
        double z = (double)b_sel2[u];
        for (int j = 0; j < 32; ++j)
            z = fma(h1[t2][j], (double)w_sel2[j * 16 + u], z);
        double m = z;
        for (int off = 8; off >= 1; off >>= 1) m = fmax(m, __shfl_xor(m, off));
        double e = exp(z - m);
        double ssum = e;
        for (int off = 8; off >= 1; off >>= 1) ssum += __shfl_xor(ssum, off);
        double pwv = e / ssum;
        pw64[(tok0 + t2) * 16 + u] = pwv;
        pw32[(tok0 + t2) * 16 + u] = (float)pwv;
    } else if (tid < 34) {   // intensity finish
        int t3 = tid - 32;
        double iv = sigmoid64(ipart[t3][0] + ipart[t3][1] + (double)b_int2[0]);
        it64[tok0 + t3] = iv;
        it32[tok0 + t3] = (float)iv;
    }
}

// ---------------- kernel 2a: x.mean(axis=1) partial sums -------------------
__global__ __launch_bounds__(256) void win_part_kernel(
    const float* __restrict__ x, double* __restrict__ wpart)
{
    __shared__ double red[2][128];
    const int tid = threadIdx.x;
    const int b = blockIdx.x >> 4, chunk = blockIdx.x & 15;
    int i = tid & 127, h = tid >> 7;
    double a0 = 0.0, a1 = 0.0;
    int s0 = b * S_ + chunk * 64 + h * 32;
    for (int j = 0; j < 32; j += 2) {
        a0 += (double)x[(s0 + j) * 128 + i];
        a1 += (double)x[(s0 + j + 1) * 128 + i];
    }
    red[h][i] = a0 + a1;
    __syncthreads();
    if (tid < 128)
        wpart[(b * 16 + chunk) * 128 + tid] = red[0][tid] + red[1][tid];
}

// ---------------- kernel 2b: finish window MLP -----------------------------
__global__ __launch_bounds__(256) void win_fin_kernel(
    const double* __restrict__ wpart,
    const float* __restrict__ w_win1, const float* __restrict__ b_win1,
    const float* __restrict__ w_win2, const float* __restrict__ b_win2,
    double* __restrict__ win_out)
{
    __shared__ double xm[4][128];
    const int tid = threadIdx.x;
    const int b = tid >> 6, lane = tid & 63;
    for (int r = 0; r < 2; ++r) {
        int i = lane + r * 64;
        double s = 0.0;
        for (int c = 0; c < 16; ++c)
            s += wpart[(b * 16 + c) * 128 + i];
        xm[b][i] = s * (1.0 / 1024.0);
    }
    __syncthreads();
    {
        int u = lane;
        double s0 = (double)b_win1[u], s1 = 0.0;
        for (int i = 0; i < 128; i += 2) {
            s0 = fma(xm[b][i],     (double)w_win1[i * 64 + u],       s0);
            s1 = fma(xm[b][i + 1], (double)w_win1[(i + 1) * 64 + u], s1);
        }
        double c = gelu64(s0 + s1) * (double)w_win2[u];
        for (int off = 32; off >= 1; off >>= 1) c += __shfl_xor(c, off);
        if (lane == 0)
            win_out[b] = sigmoid64(c + (double)b_win2[0]) * 3840.0 + 256.0;
    }
}

// ---------------- kernel 3: fp32 flow + histogram top-k + masked write -----
// 2048 blocks x 512 thr; 2 tokens/block, 32 fp32 values/thread/token.
__global__ __launch_bounds__(512, 4) void flow_kernel(
    const float* __restrict__ patterns,
    const double* __restrict__ pw64, const float* __restrict__ pw32,
    const double* __restrict__ it64, const float* __restrict__ it32,
    const double* __restrict__ win,
    float* __restrict__ out)
{
    __shared__ unsigned hist[2][NB];
    __shared__ unsigned flagBits[2][512];
    __shared__ unsigned listIdx[2][CAPL];
    __shared__ double listVal[2][CAPL];
    __shared__ float smax[2][8];
    __shared__ int sred[8];
    __shared__ int bcastB[2];
    __shared__ unsigned listCnt[2];

    const int tid = threadIdx.x;
    const int lane = tid & 63, wv = tid >> 6;
    const int t0 = blockIdx.x * 2, t1 = t0 + 1;

    // zero LDS (hist + flags + counters)
    for (int r = tid; r < 2 * NB; r += 512) hist[r >> 9][r & (NB - 1)] = 0;
    for (int r = tid; r < 1024; r += 512) flagBits[r >> 9][r & 511] = 0;
    if (tid < 2) listCnt[tid] = 0;

    // k = max(1, floor(16384 * 0.1 * mean(window/4096)))  (np fp64 order)
    double w0 = win[0] * (1.0 / 4096.0), w1 = win[1] * (1.0 / 4096.0);
    double w2 = win[2] * (1.0 / 4096.0), w3 = win[3] * (1.0 / 4096.0);
    double mean = (((w0 + w1) + w2) + w3) * 0.25;
    double kd = floor(16384.0 * (0.1 * mean));
    int k = (kd < 1.0) ? 1 : (int)kd;

    float qw0[16], qw1[16];
#pragma unroll
    for (int p = 0; p < 16; ++p) {
        qw0[p] = rfl(pw32[t0 * 16 + p]);
        qw1[p] = rfl(pw32[t1 * 16 + p]);
    }
    float i0 = rfl(it32[t0]), i1 = rfl(it32[t1]);

    const v4f* pat4 = (const v4f*)patterns;
    v4f v0[8], v1[8];
#pragma unroll
    for (int c = 0; c < 8; ++c) {
        int grp = c * 512 + tid;
        v4f a0 = (v4f)(0.0f), a1 = (v4f)(0.0f);
#pragma unroll
        for (int p = 0; p < 16; ++p) {
            v4f pp = pat4[p * 4096 + grp];
            a0 += qw0[p] * pp;
            a1 += qw1[p] * pp;
        }
        v0[c] = a0 * i0;
        v1[c] = a1 * i1;
    }

    // per-token max |v|
    float mx0 = 0.0f, mx1 = 0.0f;
#pragma unroll
    for (int c = 0; c < 8; ++c) {
        mx0 = fmaxf(mx0, fmaxf(fmaxf(fabsf(v0[c].x), fabsf(v0[c].y)),
                               fmaxf(fabsf(v0[c].z), fabsf(v0[c].w))));
        mx1 = fmaxf(mx1, fmaxf(fmaxf(fabsf(v1[c].x), fabsf(v1[c].y)),
                               fmaxf(fabsf(v1[c].z), fabsf(v1[c].w))));
    }
    for (int off = 32; off >= 1; off >>= 1) {
        mx0 = fmaxf(mx0, __shfl_xor(mx0, off));
        mx1 = fmaxf(mx1, __shfl_xor(mx1, off));
    }
    if (lane == 0) { smax[0][wv] = mx0; smax[1][wv] = mx1; }
    __syncthreads();   // #1: covers zeroing + smax
    mx0 = smax[0][0]; mx1 = smax[1][0];
#pragma unroll
    for (int w = 1; w < 8; ++w) {
        mx0 = fmaxf(mx0, smax[0][w]);
        mx1 = fmaxf(mx1, smax[1][w]);
    }
    int base0 = (int)(__float_as_uint(mx0) >> 17) - (NB - 1);
    int base1 = (int)(__float_as_uint(mx1) >> 17) - (NB - 1);
    if (base0 < 0) base0 = 0;
    if (base1 < 0) base1 = 0;

    // histogram (skip underflow bucket 0 — never contains the threshold)
#pragma unroll
    for (int c = 0; c < 8; ++c) {
#pragma unroll
        for (int q = 0; q < 4; ++q) {
            int b0 = (int)(__float_as_uint(fabsf(v0[c][q])) >> 17) - base0;
            if (b0 > 0) atomicAdd(&hist[0][b0 > NB - 1 ? NB - 1 : b0], 1u);
            int b1 = (int)(__float_as_uint(fabsf(v1[c][q])) >> 17) - base1;
            if (b1 > 0) atomicAdd(&hist[1][b1 > NB - 1 ? NB - 1 : b1], 1u);
        }
    }
    __syncthreads();   // #2

    // waves 0/1: suffix-scan to find bucket B = bucket of k-th largest
    if (wv < 2) {
        int t = wv;
        int sum8 = 0;
#pragma unroll
        for (int j = 0; j < 8; ++j) sum8 += (int)hist[t][lane * 8 + j];
        int suffix = sum8;
        for (int off = 1; off <= 32; off <<= 1) {
            int other = __shfl_down(suffix, off);
            if (lane + off < 64) suffix += other;
        }
        int sufNext = __shfl_down(suffix, 1);
        if (lane == 63) sufNext = 0;
        unsigned long long msk = __ballot(suffix >= k);
        int Lstar = (msk == 0) ? 0 : (63 - __clzll(msk));
        if (lane == Lstar) {
            int cnt = sufNext, B = Lstar * 8;
            for (int j = 7; j >= 0; --j) {
                cnt += (int)hist[t][Lstar * 8 + j];
                if (cnt >= k) { B = Lstar * 8 + j; break; }
            }
            bcastB[t] = B;
        }
    }
    __syncthreads();   // #3

    int B0 = bcastB[0], B1 = bcastB[1];
    float loF0 = (B0 + base0) ? __uint_as_float((unsigned)(B0 + base0) << 17) : 0.0f;
    float hiF0 = __uint_as_float((unsigned)(B0 + base0 + 1) << 17);
    float loF1 = (B1 + base1) ? __uint_as_float((unsigned)(B1 + base1) << 17) : 0.0f;
    float hiF1 = __uint_as_float((unsigned)(B1 + base1 + 1) << 17);

    // margins: E bounds |v32 - a64|, same constants as round 3
    float E0 = 3e-6f * i0, E1 = 3e-6f * i1;
    float loCut0 = loF0 - 2.0f * E0, hiCut0 = hiF0 + 2.0f * E0;
    float loCut1 = loF1 - 2.0f * E1, hiCut1 = hiF1 + 2.0f * E1;

    // sure-in count + candidate collection
    int ns0 = 0, ns1 = 0;
#pragma unroll
    for (int c = 0; c < 8; ++c) {
#pragma unroll
        for (int q = 0; q < 4; ++q) {
            unsigned e = (unsigned)(4 * (c * 512 + tid) + q);
            float a0 = fabsf(v0[c][q]);
            if (a0 >= hiCut0) ns0++;
            else if (a0 >= loCut0) {
                unsigned pos = atomicAdd(&listCnt[0], 1u);
                if (pos < CAPL) listIdx[0][pos] = e;
            }
            float a1 = fabsf(v1[c][q]);
            if (a1 >= hiCut1) ns1++;
            else if (a1 >= loCut1) {
                unsigned pos = atomicAdd(&listCnt[1], 1u);
                if (pos < CAPL) listIdx[1][pos] = e;
            }
        }
    }
    {
        int pk = ns0 | (ns1 << 16);
#pragma unroll
        for (int off = 32; off >= 1; off >>= 1) pk += __shfl_xor(pk, off);
        if (lane == 0) sred[wv] = pk;
    }
    __syncthreads();   // #4
    int tot = 0;
#pragma unroll
    for (int w = 0; w < 8; ++w) tot += sred[w];
    int m0 = k - (tot & 0xffff), m1 = k - (tot >> 16);
    int c0n = (int)(listCnt[0] < CAPL ? listCnt[0] : CAPL);
    int c1n = (int)(listCnt[1] < CAPL ? listCnt[1] : CAPL);

    // fp64-exact values for candidates (matches np ranking to ~1e-15)
    double itt0 = it64[t0], itt1 = it64[t1];
    int totL = c0n + c1n;
    for (int g = tid; g < totL; g += 512) {
        int tk = (g >= c0n);
        int e = tk ? (g - c0n) : g;
        unsigned idx = listIdx[tk][e];
        const double* pwp = pw64 + (tk ? t1 : t0) * 16;
        double s = 0.0;
#pragma unroll
        for (int p = 0; p < 16; ++p)
            s = fma(pwp[p], (double)patterns[p * D_ + idx], s);
        listVal[tk][e] = fabs(s * (tk ? itt1 : itt0));
    }
    __syncthreads();   // #5
    // rank within list; keep iff (#strictly-greater) < m   [tie-correct]
    for (int g = tid; g < totL; g += 512) {
        int tk = (g >= c0n);
        int e = tk ? (g - c0n) : g;
        double my = listVal[tk][e];
        int cnt = tk ? c1n : c0n, m = tk ? m1 : m0;
        int r = 0;
        for (int j = 0; j < cnt; ++j) r += (listVal[tk][j] > my);
        if (r < m) {
            unsigned idx = listIdx[tk][e];
            atomicOr(&flagBits[tk][idx >> 5], 1u << (idx & 31));
        }
    }
    __syncthreads();   // #6

    // masked write
    v4f* o0p = (v4f*)(out + (size_t)t0 * D_);
    v4f* o1p = (v4f*)(out + (size_t)t1 * D_);
#pragma unroll
    for (int c = 0; c < 8; ++c) {
        int grp = c * 512 + tid;
        v4f r0, r1;
#pragma unroll
        for (int q = 0; q < 4; ++q) {
            unsigned e = (unsigned)(4 * grp + q);
            float av = fabsf(v0[c][q]);
            bool keep = (av >= hiCut0);
            if (!keep && av >= loCut0) keep = (flagBits[0][e >> 5] >> (e & 31)) & 1u;
            r0[q] = keep ? v0[c][q] : 0.0f;
            av = fabsf(v1[c][q]);
            keep = (av >= hiCut1);
            if (!keep && av >= loCut1) keep = (flagBits[1][e >> 5] >> (e & 31)) & 1u;
            r1[q] = keep ? v1[c][q] : 0.0f;
        }
        __builtin_nontemporal_store(r0, &o0p[grp]);
        __builtin_nontemporal_store(r1, &o1p[grp]);
    }
}

extern "C" void kernel_launch(void* const* d_in, const int* in_sizes, int n_in,
                              void* d_out, int out_size, void* d_ws, size_t ws_size,
                              hipStream_t stream) {
    const float* x        = (const float*)d_in[0];
    const float* ctx      = (const float*)d_in[1];
    const float* patterns = (const float*)d_in[2];
    const float* w_sel1   = (const float*)d_in[3];
    const float* b_sel1   = (const float*)d_in[4];
    const float* w_sel2   = (const float*)d_in[5];
    const float* b_sel2   = (const float*)d_in[6];
    const float* w_int1   = (const float*)d_in[7];
    const float* b_int1   = (const float*)d_in[8];
    const float* w_int2   = (const float*)d_in[9];
    const float* b_int2   = (const float*)d_in[10];
    const float* w_win1   = (const float*)d_in[11];
    const float* b_win1   = (const float*)d_in[12];
    const float* w_win2   = (const float*)d_in[13];
    const float* b_win2   = (const float*)d_in[14];

    double* ws    = (double*)d_ws;
    double* win   = ws;                   // 8 doubles reserved
    double* pw64  = ws + 8;               // 65536
    double* it64  = pw64 + 65536;         // 4096
    double* wpart = it64 + 4096;          // 8192
    float*  pw32  = (float*)(wpart + 8192);  // 65536 floats
    float*  it32  = pw32 + 65536;            // 4096 floats
    float*  out   = (float*)d_out;

    hipLaunchKernelGGL(mlp_kernel, dim3(2048), dim3(256), 0, stream,
                       x, ctx, w_sel1, b_sel1, w_sel2, b_sel2,
                       w_int1, b_int1, w_int2, b_int2, pw64, pw32, it64, it32);
    hipLaunchKernelGGL(win_part_kernel, dim3(64), dim3(256), 0, stream, x, wpart);
    hipLaunchKernelGGL(win_fin_kernel, dim3(1), dim3(256), 0, stream,
                       wpart, w_win1, b_win1, w_win2, b_win2, win);
    hipLaunchKernelGGL(flow_kernel, dim3(2048), dim3(512), 0, stream,
                       patterns, pw64, pw32, it64, it32, win, out);
}